// Round 5
// baseline (140.699 us; speedup 1.0000x reference)
//
#include <hip/hip_runtime.h>

typedef _Float16 f16;
typedef f16 f16x8 __attribute__((ext_vector_type(8)));
typedef float f32x16 __attribute__((ext_vector_type(16)));
typedef float f32x4v __attribute__((ext_vector_type(4)));

#define IMG_H 1024
#define IMG_W 1024
#define CIN 64
#define COUT_ 64
#define NBLK 32
#define NACT 512
#define EPS_ 1e-3f

#define WT_ELEMS (36 * 2 * 64 * 8)   // 36864 f16 fragments
#define WT_WGS   144                 // 144*256 == WT_ELEMS
#define FLAGS_OFF (WT_ELEMS * 2)

// Weight fragments for mfma_f32_32x32x16_f16 (lane layout verified R2; same
// bytes serve as A-operand with m=cout since A/B lane layouts coincide):
//   kstep ks = tap*4 + q ; lane l elem j: k=(l>>5)*8+j -> cin = q*16+(l>>5)*8+j
//   m/col = l&31 -> cout = ch*32 + (l&31)
__global__ void prep_k(const float* __restrict__ w, const int* __restrict__ abi,
                       f16* __restrict__ wt, int* __restrict__ flags) {
    int wg = blockIdx.x;
    if (wg == WT_WGS) {
        int tid = threadIdx.x;
        for (int i = tid; i < NBLK * NBLK; i += 256) flags[i] = 0;
        __syncthreads();
        for (int t = tid; t < NACT; t += 256) {
            int bi = abi[3 * t + 1];
            int bj = abi[3 * t + 2];
            flags[bi * NBLK + bj] = 1;
        }
        return;
    }
    int t = wg * 256 + threadIdx.x;
    int j  = t & 7;
    int l  = (t >> 3) & 63;
    int ch = (t >> 9) & 1;
    int ks = t >> 10;                 // 0..35
    int tap = ks >> 2, q = ks & 3;
    int ky = tap / 3, kx = tap % 3;
    int cin  = q * 16 + ((l >> 5) << 3) + j;
    int cout = ch * 32 + (l & 31);
    wt[t] = (f16)w[((ky * 3 + kx) * CIN + cin) * COUT_ + cout];
}

__launch_bounds__(256, 2)
__global__ void fused_k(const float* __restrict__ inp,
                        const f16*  __restrict__ wt,
                        const float* __restrict__ cb,
                        const float* __restrict__ gamma,
                        const float* __restrict__ beta,
                        const float* __restrict__ rmean,
                        const float* __restrict__ rvar,
                        const int*  __restrict__ abi,
                        const int*  __restrict__ flags,
                        float* __restrict__ out) {
    // patch: 18 rows x 34 cols x 8 channel-groups of 16B (f16x8), XOR-swizzled
    __shared__ uint4 lds[18 * 34 * 8];   // 78336 B -> 2 wg/CU
    __shared__ float scs[64], shs[64];

    const int wg  = blockIdx.x;
    const int tid = threadIdx.x;

    if (wg & 1) {
        // ---- zero-duty: one wg per (bi,bj); zero if inactive ----
        int b = wg >> 1;
        if (flags[b]) return;
        int bi = b >> 5, bj = b & 31;
        f32x4v z = {0.f, 0.f, 0.f, 0.f};
        f32x4v* base = (f32x4v*)(out + ((size_t)(bi * 32) * IMG_W + bj * 32) * COUT_);
        for (int it = tid; it < 32 * 512; it += 256) {
            int r  = it >> 9;
            int c4 = it & 511;
            __builtin_nontemporal_store(z, &base[(size_t)r * (IMG_W * COUT_ / 4) + c4]);
        }
        return;
    }

    // ---- conv duty: one wg per half-block (16 rows x 32 cols) ----
    const int ci = wg >> 1;
    const int ab = ci >> 1, yh = ci & 1;
    const int bi = abi[3 * ab + 1];
    const int bj = abi[3 * ab + 2];
    const int lane = tid & 63;
    const int wv   = tid >> 6;

    // BN scale/shift table (64 couts)
    if (tid < 64) {
        float sc = gamma[tid] * rsqrtf(rvar[tid] + EPS_);
        scs[tid] = sc;
        shs[tid] = cb[tid] * sc + beta[tid] - rmean[tid] * sc;
    }

    // stage 18x34x64 patch (fp32 -> f16, swizzled channel groups)
    const int r0 = bi * 32 + yh * 16 - 1;
    const int c0 = bj * 32 - 1;
    for (int task = tid; task < 18 * 34 * 8; task += 256) {
        int g  = task & 7;
        int p  = task >> 3;
        int dr = p / 34;
        int dc = p - dr * 34;
        int row = r0 + dr, col = c0 + dc;
        float4 a = make_float4(0.f, 0.f, 0.f, 0.f), b = a;
        if ((unsigned)row < IMG_H && (unsigned)col < IMG_W) {
            const float4* src = (const float4*)(inp + (((size_t)row * IMG_W + col) * CIN + g * 8));
            a = src[0]; b = src[1];
        }
        f16x8 v;
        v[0] = (f16)a.x; v[1] = (f16)a.y; v[2] = (f16)a.z; v[3] = (f16)a.w;
        v[4] = (f16)b.x; v[5] = (f16)b.y; v[6] = (f16)b.z; v[7] = (f16)b.w;
        lds[(p << 3) + (g ^ (dc & 7))] = __builtin_bit_cast(uint4, v);
    }

    // per-wave weight fragments: wave = (row-group rg, cout-half chh)
    const int rg  = wv & 1;
    const int chh = wv >> 1;
    f16x8 wf[36];
    const uint4* wt4 = (const uint4*)wt;
    #pragma unroll
    for (int ks = 0; ks < 36; ++ks)
        wf[ks] = __builtin_bit_cast(f16x8, wt4[(ks * 2 + chh) * 64 + lane]);

    __syncthreads();

    const int px = lane & 31;      // B col = output pixel column
    const int hi = lane >> 5;      // k sub-group
    // base ptr: row R=0 of this tile, pixel px, cout chh*32 + hi*4
    float* outb = out + (((size_t)(bi * 32 + yh * 16) * IMG_W) + bj * 32 + px) * COUT_
                      + chh * 32 + hi * 4;

    for (int yr = 0; yr < 8; ++yr) {
        const int R = rg * 8 + yr;
        f32x16 accA = {0.f,0.f,0.f,0.f,0.f,0.f,0.f,0.f,0.f,0.f,0.f,0.f,0.f,0.f,0.f,0.f};
        f32x16 accB = {0.f,0.f,0.f,0.f,0.f,0.f,0.f,0.f,0.f,0.f,0.f,0.f,0.f,0.f,0.f,0.f};
        #pragma unroll
        for (int ks = 0; ks < 36; ++ks) {
            const int tap = ks >> 2, q = ks & 3;
            const int ky = tap / 3, kx = tap % 3;
            const int dr = R + ky;
            const int dc = px + kx;
            const int slot = (q * 2 + hi) ^ (dc & 7);
            uint4 a = lds[((dr * 34 + dc) << 3) + slot];
            if (ks & 1)
                accB = __builtin_amdgcn_mfma_f32_32x32x16_f16(wf[ks], __builtin_bit_cast(f16x8, a), accB, 0, 0, 0);
            else
                accA = __builtin_amdgcn_mfma_f32_32x32x16_f16(wf[ks], __builtin_bit_cast(f16x8, a), accA, 0, 0, 0);
        }
        #pragma unroll
        for (int g4 = 0; g4 < 4; ++g4) {
            const int cbase = chh * 32 + g4 * 8 + hi * 4;
            f32x4v sv = *(const f32x4v*)&scs[cbase];
            f32x4v hv = *(const f32x4v*)&shs[cbase];
            f32x4v v;
            #pragma unroll
            for (int u = 0; u < 4; ++u) {
                float x = (accA[4 * g4 + u] + accB[4 * g4 + u]) * sv[u] + hv[u];
                v[u] = fmaxf(x, 0.f);
            }
            *(f32x4v*)(outb + (size_t)R * IMG_W * COUT_ + g4 * 8) = v;
        }
    }
}

extern "C" void kernel_launch(void* const* d_in, const int* in_sizes, int n_in,
                              void* d_out, int out_size, void* d_ws, size_t ws_size,
                              hipStream_t stream) {
    const float* inp   = (const float*)d_in[0];
    const float* convw = (const float*)d_in[1];
    const float* convb = (const float*)d_in[2];
    const float* gamma = (const float*)d_in[3];
    const float* beta  = (const float*)d_in[4];
    const float* rmean = (const float*)d_in[5];
    const float* rvar  = (const float*)d_in[6];
    const int*   abi   = (const int*)d_in[7];
    float* out = (float*)d_out;

    f16* wt    = (f16*)d_ws;
    int* flags = (int*)((char*)d_ws + FLAGS_OFF);

    hipLaunchKernelGGL(prep_k, dim3(WT_WGS + 1), dim3(256), 0, stream, convw, abi, wt, flags);
    hipLaunchKernelGGL(fused_k, dim3(2 * 2 * NACT), dim3(256), 0, stream,
                       inp, wt, convb, gamma, beta, rmean, rvar, abi, flags, out);
}

// Round 6
// 113.107 us; speedup vs baseline: 1.2439x; 1.2439x over previous
//
#include <hip/hip_runtime.h>

typedef _Float16 f16;
typedef f16 f16x8 __attribute__((ext_vector_type(8)));
typedef float f32x16 __attribute__((ext_vector_type(16)));
typedef float f32x4v __attribute__((ext_vector_type(4)));

#define IMG_H 1024
#define IMG_W 1024
#define CIN 64
#define COUT_ 64
#define NBLK 32
#define NACT 512
#define EPS_ 1e-3f

#define WT_ELEMS (36 * 2 * 64 * 8)   // 36864 f16 fragments
#define WT_WGS   144                 // 144*256 == WT_ELEMS
#define FLAGS_OFF (WT_ELEMS * 2)

// Weight fragments for mfma_f32_32x32x16_f16 (lane layout verified R2/R5):
//   kstep ks = tap*4 + q ; lane l elem j: k=(l>>5)*8+j -> cin = q*16+(l>>5)*8+j
//   m/col = l&31 -> cout = ch*32 + (l&31)
__global__ void prep_k(const float* __restrict__ w, const int* __restrict__ abi,
                       f16* __restrict__ wt, int* __restrict__ flags) {
    int wg = blockIdx.x;
    if (wg == WT_WGS) {
        int tid = threadIdx.x;
        for (int i = tid; i < NBLK * NBLK; i += 256) flags[i] = 0;
        __syncthreads();
        for (int t = tid; t < NACT; t += 256) {
            int bi = abi[3 * t + 1];
            int bj = abi[3 * t + 2];
            flags[bi * NBLK + bj] = 1;
        }
        return;
    }
    int t = wg * 256 + threadIdx.x;
    int j  = t & 7;
    int l  = (t >> 3) & 63;
    int ch = (t >> 9) & 1;
    int ks = t >> 10;                 // 0..35
    int tap = ks >> 2, q = ks & 3;
    int ky = tap / 3, kx = tap % 3;
    int cin  = q * 16 + ((l >> 5) << 3) + j;
    int cout = ch * 32 + (l & 31);
    wt[t] = (f16)w[((ky * 3 + kx) * CIN + cin) * COUT_ + cout];
}

__launch_bounds__(256, 2)
__global__ void fused_k(const float* __restrict__ inp,
                        const f16*  __restrict__ wt,
                        const float* __restrict__ cb,
                        const float* __restrict__ gamma,
                        const float* __restrict__ beta,
                        const float* __restrict__ rmean,
                        const float* __restrict__ rvar,
                        const int*  __restrict__ abi,
                        const int*  __restrict__ flags,
                        float* __restrict__ out) {
    // patch: 18 rows x 34 cols x 8 channel-groups of 16B (f16x8), XOR-swizzled
    __shared__ uint4 lds[18 * 34 * 8];   // 78336 B -> 2 wg/CU
    __shared__ float scs[64], shs[64];

    const int wg  = blockIdx.x;
    const int tid = threadIdx.x;

    if (wg >= 2 * NACT) {
        // ---- zero-duty (tail of grid): one wg per (bi,bj); zero if inactive ----
        int b = wg - 2 * NACT;
        if (flags[b]) return;
        int bi = b >> 5, bj = b & 31;
        float4 z = make_float4(0.f, 0.f, 0.f, 0.f);
        float4* base = (float4*)(out + ((size_t)(bi * 32) * IMG_W + bj * 32) * COUT_);
        for (int it = tid; it < 32 * 512; it += 256) {
            int r  = it >> 9;
            int c4 = it & 511;
            base[(size_t)r * (IMG_W * COUT_ / 4) + c4] = z;
        }
        return;
    }

    // ---- conv duty: one wg per half-block (16 rows x 32 cols) ----
    const int ci = wg;
    const int ab = ci >> 1, yh = ci & 1;
    const int bi = abi[3 * ab + 1];
    const int bj = abi[3 * ab + 2];
    const int lane = tid & 63;
    const int wv   = tid >> 6;

    // BN scale/shift table (64 couts)
    if (tid < 64) {
        float sc = gamma[tid] * rsqrtf(rvar[tid] + EPS_);
        scs[tid] = sc;
        shs[tid] = cb[tid] * sc + beta[tid] - rmean[tid] * sc;
    }

    // stage 18x34x64 patch (fp32 -> f16, swizzled channel groups)
    const int r0 = bi * 32 + yh * 16 - 1;
    const int c0 = bj * 32 - 1;
    for (int task = tid; task < 18 * 34 * 8; task += 256) {
        int g  = task & 7;
        int p  = task >> 3;
        int dr = p / 34;
        int dc = p - dr * 34;
        int row = r0 + dr, col = c0 + dc;
        float4 a = make_float4(0.f, 0.f, 0.f, 0.f), b = a;
        if ((unsigned)row < IMG_H && (unsigned)col < IMG_W) {
            const float4* src = (const float4*)(inp + (((size_t)row * IMG_W + col) * CIN + g * 8));
            a = src[0]; b = src[1];
        }
        f16x8 v;
        v[0] = (f16)a.x; v[1] = (f16)a.y; v[2] = (f16)a.z; v[3] = (f16)a.w;
        v[4] = (f16)b.x; v[5] = (f16)b.y; v[6] = (f16)b.z; v[7] = (f16)b.w;
        lds[(p << 3) + (g ^ (dc & 7))] = __builtin_bit_cast(uint4, v);
    }

    // per-wave weight fragments: wave = (row-group rg, cout-half chh)
    const int rg  = wv & 1;
    const int chh = wv >> 1;
    f16x8 wf[36];
    const uint4* wt4 = (const uint4*)wt;
    #pragma unroll
    for (int ks = 0; ks < 36; ++ks)
        wf[ks] = __builtin_bit_cast(f16x8, wt4[(ks * 2 + chh) * 64 + lane]);

    __syncthreads();

    const int px = lane & 31;      // B col = output pixel column
    const int hi = lane >> 5;      // k sub-group
    float* outb = out + (((size_t)(bi * 32 + yh * 16) * IMG_W) + bj * 32 + px) * COUT_
                      + chh * 32 + hi * 4;

    for (int yr = 0; yr < 8; ++yr) {
        const int R = rg * 8 + yr;
        f32x16 accA = {0.f,0.f,0.f,0.f,0.f,0.f,0.f,0.f,0.f,0.f,0.f,0.f,0.f,0.f,0.f,0.f};
        f32x16 accB = {0.f,0.f,0.f,0.f,0.f,0.f,0.f,0.f,0.f,0.f,0.f,0.f,0.f,0.f,0.f,0.f};
        #pragma unroll
        for (int ks = 0; ks < 36; ++ks) {
            const int tap = ks >> 2, q = ks & 3;
            const int ky = tap / 3, kx = tap % 3;
            const int dr = R + ky;
            const int dc = px + kx;
            const int slot = (q * 2 + hi) ^ (dc & 7);
            uint4 a = lds[((dr * 34 + dc) << 3) + slot];
            if (ks & 1)
                accB = __builtin_amdgcn_mfma_f32_32x32x16_f16(wf[ks], __builtin_bit_cast(f16x8, a), accB, 0, 0, 0);
            else
                accA = __builtin_amdgcn_mfma_f32_32x32x16_f16(wf[ks], __builtin_bit_cast(f16x8, a), accA, 0, 0, 0);
        }
        #pragma unroll
        for (int g4 = 0; g4 < 4; ++g4) {
            const int cbase = chh * 32 + g4 * 8 + hi * 4;
            f32x4v sv = *(const f32x4v*)&scs[cbase];
            f32x4v hv = *(const f32x4v*)&shs[cbase];
            f32x4v v;
            #pragma unroll
            for (int u = 0; u < 4; ++u) {
                float x = (accA[4 * g4 + u] + accB[4 * g4 + u]) * sv[u] + hv[u];
                v[u] = fmaxf(x, 0.f);
            }
            *(f32x4v*)(outb + (size_t)R * IMG_W * COUT_ + g4 * 8) = v;
        }
    }
}

extern "C" void kernel_launch(void* const* d_in, const int* in_sizes, int n_in,
                              void* d_out, int out_size, void* d_ws, size_t ws_size,
                              hipStream_t stream) {
    const float* inp   = (const float*)d_in[0];
    const float* convw = (const float*)d_in[1];
    const float* convb = (const float*)d_in[2];
    const float* gamma = (const float*)d_in[3];
    const float* beta  = (const float*)d_in[4];
    const float* rmean = (const float*)d_in[5];
    const float* rvar  = (const float*)d_in[6];
    const int*   abi   = (const int*)d_in[7];
    float* out = (float*)d_out;

    f16* wt    = (f16*)d_ws;
    int* flags = (int*)((char*)d_ws + FLAGS_OFF);

    hipLaunchKernelGGL(prep_k, dim3(WT_WGS + 1), dim3(256), 0, stream, convw, abi, wt, flags);
    hipLaunchKernelGGL(fused_k, dim3(2 * NACT + NBLK * NBLK), dim3(256), 0, stream,
                       inp, wt, convb, gamma, beta, rmean, rvar, abi, flags, out);
}